// Round 12
// baseline (320.299 us; speedup 1.0000x reference)
//
#include <hip/hip_runtime.h>
#include <math.h>

#define DIMC 768
#define BATCH 16
#define HWSZ 1024
#define NT 32

// out layout: result [16*32*768] | p [16*32*768] | mask [16*32*1024]
#define OUT_P_OFF    393216
#define OUT_MASK_OFF 786432

typedef float v4f __attribute__((ext_vector_type(4)));

// ---------------- K0: pack params; fold 1/6 into pw weights ----------------
// pk[c][12] = { w0..w8, dwb, bn_scale, bn_shift }  (BN per tap in KF; folding
// shift into bias is WRONG at zero-padded borders -- round-9 bug)
// wt[c][t]  = pww[t][c] / 6   (hardswish divisor folded in; exact)
__global__ __launch_bounds__(256) void k0_prep(
    const float* __restrict__ pww,
    const float* __restrict__ dww, const float* __restrict__ dwb,
    const float* __restrict__ bnw, const float* __restrict__ bnb,
    const float* __restrict__ bnm, const float* __restrict__ bnv,
    float* __restrict__ wt, float* __restrict__ pk)
{
    int i = blockIdx.x * 256 + threadIdx.x;
    if (i < 24576) wt[i] = pww[(i & 31) * DIMC + (i >> 5)] * (1.0f / 6.0f);
    int c = i - 24576;
    if (c >= 0 && c < DIMC) {
        float* o = pk + c * 12;
#pragma unroll
        for (int j = 0; j < 9; ++j) o[j] = dww[c * 9 + j];
        o[9] = dwb[c];
        float scale = bnw[c] * rsqrtf(bnv[c] + 1e-5f);
        o[10] = scale;
        o[11] = bnb[c] - bnm[c] * scale;
    }
}

// ---------------- KF: fused BN + dw3x3 + hardswish + pointwise -------------
// NO LDS. Lane owns a 1x2 output strip; 3x4 window = 9 global loads.
// BN per tap: tap = fmaf(x, scale, shift) * mask (mask=0 -> f-space zero pad).
// Depth-3 register prefetch; occupancy via grid: 1024 blocks = 4/CU = 16 w/CU.

#define DECL_SET(S) float S##l0, S##r0, S##l1, S##r1, S##l2, S##r2; \
                    float2 S##m0, S##m1, S##m2;

#define XLOAD(S, xc) { \
    S##l0 = (xc)[oL0]; S##m0 = *(const float2*)((xc) + oM0); S##r0 = (xc)[oR0]; \
    S##l1 = (xc)[oL1]; S##m1 = *(const float2*)((xc) + oM1); S##r1 = (xc)[oR1]; \
    S##l2 = (xc)[oL2]; S##m2 = *(const float2*)((xc) + oM2); S##r2 = (xc)[oR2]; }

#define STEP(k, S, ISSUE) { \
    const float* pr = pkb + (k) * 12; \
    v4f P0 = *(const v4f*)pr; \
    v4f P1 = *(const v4f*)(pr + 4); \
    v4f P2 = *(const v4f*)(pr + 8);      /* {w8, dwb, scale, shift} */ \
    const float sc_ = P2.z, sh_ = P2.w; \
    float a0  = fmaf(S##l0,   sc_, sh_) * mL0; \
    float b0x = fmaf(S##m0.x, sc_, sh_) * mM0; \
    float b0y = fmaf(S##m0.y, sc_, sh_) * mM0; \
    float c0  = fmaf(S##r0,   sc_, sh_) * mR0; \
    float a1  = fmaf(S##l1,   sc_, sh_) * mL1; \
    float b1x = fmaf(S##m1.x, sc_, sh_) * mM1; \
    float b1y = fmaf(S##m1.y, sc_, sh_) * mM1; \
    float c1  = fmaf(S##r1,   sc_, sh_) * mR1; \
    float a2  = fmaf(S##l2,   sc_, sh_) * mL2; \
    float b2x = fmaf(S##m2.x, sc_, sh_) * mM2; \
    float b2y = fmaf(S##m2.y, sc_, sh_) * mM2; \
    float c2  = fmaf(S##r2,   sc_, sh_) * mR2; \
    if (ISSUE) { XLOAD(S, xcur); xcur += HWSZ; } \
    float s0 = P2.y, s1 = P2.y; \
    s0 = fmaf(P0.x, a0,  s0); s1 = fmaf(P0.x, b0x, s1); \
    s0 = fmaf(P0.y, b0x, s0); s1 = fmaf(P0.y, b0y, s1); \
    s0 = fmaf(P0.z, b0y, s0); s1 = fmaf(P0.z, c0,  s1); \
    s0 = fmaf(P0.w, a1,  s0); s1 = fmaf(P0.w, b1x, s1); \
    s0 = fmaf(P1.x, b1x, s0); s1 = fmaf(P1.x, b1y, s1); \
    s0 = fmaf(P1.y, b1y, s0); s1 = fmaf(P1.y, c1,  s1); \
    s0 = fmaf(P1.z, a2,  s0); s1 = fmaf(P1.z, b2x, s1); \
    s0 = fmaf(P1.w, b2x, s0); s1 = fmaf(P1.w, b2y, s1); \
    s0 = fmaf(P2.x, b2y, s0); s1 = fmaf(P2.x, c2,  s1); \
    float h0 = s0 * fminf(fmaxf(s0 + 3.0f, 0.0f), 6.0f); \
    float h1 = s1 * fminf(fmaxf(s1 + 3.0f, 0.0f), 6.0f); \
    v4f hv0 = {h0, h0, h0, h0}, hv1 = {h1, h1, h1, h1}; \
    const v4f* wr = (const v4f*)(wtb + (k) * NT); \
    A0 = __builtin_elementwise_fma(hv0, wr[0], A0); B0 = __builtin_elementwise_fma(hv1, wr[0], B0); \
    A1 = __builtin_elementwise_fma(hv0, wr[1], A1); B1 = __builtin_elementwise_fma(hv1, wr[1], B1); \
    A2 = __builtin_elementwise_fma(hv0, wr[2], A2); B2 = __builtin_elementwise_fma(hv1, wr[2], B2); \
    A3 = __builtin_elementwise_fma(hv0, wr[3], A3); B3 = __builtin_elementwise_fma(hv1, wr[3], B3); \
    A4 = __builtin_elementwise_fma(hv0, wr[4], A4); B4 = __builtin_elementwise_fma(hv1, wr[4], B4); \
    A5 = __builtin_elementwise_fma(hv0, wr[5], A5); B5 = __builtin_elementwise_fma(hv1, wr[5], B5); \
    A6 = __builtin_elementwise_fma(hv0, wr[6], A6); B6 = __builtin_elementwise_fma(hv1, wr[6], B6); \
    A7 = __builtin_elementwise_fma(hv0, wr[7], A7); B7 = __builtin_elementwise_fma(hv1, wr[7], B7); }

#define ST4(G) { \
    float2 v; \
    v.x = A##G.x; v.y = B##G.x; *(float2*)(po + ((4*G+0) << 10)) = v; \
    v.x = A##G.y; v.y = B##G.y; *(float2*)(po + ((4*G+1) << 10)) = v; \
    v.x = A##G.z; v.y = B##G.z; *(float2*)(po + ((4*G+2) << 10)) = v; \
    v.x = A##G.w; v.y = B##G.w; *(float2*)(po + ((4*G+3) << 10)) = v; }

template<int CHPB>
__global__ __launch_bounds__(256, 4) void kf_fused(
    const float* __restrict__ x,
    const float* __restrict__ wt, const float* __restrict__ pk,
    float* __restrict__ partials)
{
    const int b    = blockIdx.z;
    const int scc  = blockIdx.y;
    const int cb0  = scc * CHPB;
    const int tid  = threadIdx.x;
    const int wv   = tid >> 6;
    const int lane = tid & 63;
    const int rl   = lane >> 4;               // 0..3
    const int cp   = lane & 15;
    const int col0 = cp * 2;
    const int gr0  = blockIdx.x * 16 + wv * 4 + rl;   // output row 0..31

    // window geometry: rows gr0-1..gr0+1, cols col0-1..col0+2
    // clamped offsets (always-safe loads) + 0/1 mask floats (f-space zero pad)
    int gr, grc; float rv;
    gr = gr0 - 1; grc = gr < 0 ? 0 : (gr > 31 ? 31 : gr);
    rv = (gr >= 0 && gr < 32) ? 1.0f : 0.0f;
    const int   oM0 = grc * 32 + col0;
    const int   oL0 = grc * 32 + (cp ? col0 - 1 : 0);
    const int   oR0 = grc * 32 + (cp < 15 ? col0 + 2 : 31);
    const float mM0 = rv, mL0 = cp ? rv : 0.0f, mR0 = (cp < 15) ? rv : 0.0f;
    gr = gr0;
    const int   oM1 = gr * 32 + col0;
    const int   oL1 = gr * 32 + (cp ? col0 - 1 : 0);
    const int   oR1 = gr * 32 + (cp < 15 ? col0 + 2 : 31);
    const float mM1 = 1.0f, mL1 = cp ? 1.0f : 0.0f, mR1 = (cp < 15) ? 1.0f : 0.0f;
    gr = gr0 + 1; grc = gr > 31 ? 31 : gr;
    rv = (gr < 32) ? 1.0f : 0.0f;
    const int   oM2 = grc * 32 + col0;
    const int   oL2 = grc * 32 + (cp ? col0 - 1 : 0);
    const int   oR2 = grc * 32 + (cp < 15 ? col0 + 2 : 31);
    const float mM2 = rv, mL2 = cp ? rv : 0.0f, mR2 = (cp < 15) ? rv : 0.0f;

    const float* xb  = x  + (size_t)(b * DIMC + cb0) * HWSZ;
    const float* pkb = pk + (size_t)cb0 * 12;
    const float* wtb = wt + (size_t)cb0 * NT;

    DECL_SET(SA) DECL_SET(SB) DECL_SET(SC)

    // prologue: prefetch channels 0..2 (depth 3)
    const float* xcur = xb;
    XLOAD(SA, xcur); xcur += HWSZ;
    XLOAD(SB, xcur); xcur += HWSZ;
    XLOAD(SC, xcur); xcur += HWSZ;

    v4f A0 = {0,0,0,0}, A1 = {0,0,0,0}, A2 = {0,0,0,0}, A3 = {0,0,0,0};
    v4f A4 = {0,0,0,0}, A5 = {0,0,0,0}, A6 = {0,0,0,0}, A7 = {0,0,0,0};
    v4f B0 = {0,0,0,0}, B1 = {0,0,0,0}, B2 = {0,0,0,0}, B3 = {0,0,0,0};
    v4f B4 = {0,0,0,0}, B5 = {0,0,0,0}, B6 = {0,0,0,0}, B7 = {0,0,0,0};

    for (int k = 0; k < CHPB - 3; k += 3) {
        STEP(k + 0, SA, 1)
        STEP(k + 1, SB, 1)
        STEP(k + 2, SC, 1)
    }
    STEP(CHPB - 3, SA, 0)
    STEP(CHPB - 2, SB, 0)
    STEP(CHPB - 1, SC, 0)

    // epilogue: token t gets float2 {pos, pos+1}
    const int pos = gr0 * 32 + col0;
    float* po = partials + ((size_t)(scc * BATCH + b) * NT) * HWSZ + pos;
    ST4(0) ST4(1) ST4(2) ST4(3) ST4(4) ST4(5) ST4(6) ST4(7)
}

// ---------------- K3: sum partials -> argmax mask -> gather-sum ------------
template<int SCHT>
__global__ __launch_bounds__(256) void k3_mask_gather(
    const float* __restrict__ partials,
    const float* __restrict__ x, const float* __restrict__ posin,
    const float* __restrict__ bnw, const float* __restrict__ bnb,
    const float* __restrict__ bnm, const float* __restrict__ bnv,
    float* __restrict__ out)
{
    int bt = blockIdx.x;           // b*32 + t
    int b  = bt >> 5;
    int t  = bt & 31;
    int tid = threadIdx.x;

    const float4* pp4 = (const float4*)(partials + ((size_t)(b * NT) + t) * HWSZ) + tid;
    float4 acc = make_float4(0.f, 0.f, 0.f, 0.f);
#pragma unroll
    for (int s = 0; s < SCHT; ++s) {
        float4 u = pp4[(size_t)s * (BATCH * NT * HWSZ / 4)];
        acc.x += u.x; acc.y += u.y; acc.z += u.z; acc.w += u.w;
    }

    float m = fmaxf(fmaxf(acc.x, acc.y), fmaxf(acc.z, acc.w));
#pragma unroll
    for (int off = 32; off; off >>= 1)
        m = fmaxf(m, __shfl_xor(m, off));
    __shared__ float wm[4];
    if ((tid & 63) == 0) wm[tid >> 6] = m;
    __syncthreads();
    m = fmaxf(fmaxf(wm[0], wm[1]), fmaxf(wm[2], wm[3]));

    __shared__ int nmatch;
    __shared__ int matchpos[16];
    if (tid == 0) nmatch = 0;
    __syncthreads();

    float* maskp = out + OUT_MASK_OFF + (size_t)bt * HWSZ;
    float4 mask4;
    const float* av = &acc.x;
    float* mv = &mask4.x;
#pragma unroll
    for (int j = 0; j < 4; ++j) {
        int hit = (av[j] == m);
        mv[j] = hit ? 1.0f : 0.0f;
        if (hit) {
            int k = atomicAdd(&nmatch, 1);
            if (k < 16) matchpos[k] = 4 * tid + j;
        }
    }
    ((float4*)maskp)[tid] = mask4;
    __syncthreads();
    int nm = nmatch < 16 ? nmatch : 16;

    const float* xb = x + (size_t)b * DIMC * HWSZ;
    const float* pb = posin + (size_t)b * DIMC * HWSZ;
    for (int c = tid; c < DIMC; c += 256) {
        float scale = bnw[c] * rsqrtf(bnv[c] + 1e-5f);
        float shift = bnb[c] - bnm[c] * scale;
        float rf = 0.0f, rp = 0.0f;
        for (int k = 0; k < nm; ++k) {
            int pos = matchpos[k];
            rf += xb[(size_t)c * HWSZ + pos] * scale + shift;
            rp += pb[(size_t)c * HWSZ + pos];
        }
        out[(size_t)bt * DIMC + c] = rf;
        out[OUT_P_OFF + (size_t)bt * DIMC + c] = rp;
    }
}

extern "C" void kernel_launch(void* const* d_in, const int* in_sizes, int n_in,
                              void* d_out, int out_size, void* d_ws, size_t ws_size,
                              hipStream_t stream)
{
    const float* x    = (const float*)d_in[0];
    const float* pos  = (const float*)d_in[1];
    const float* bnw  = (const float*)d_in[2];
    const float* bnb  = (const float*)d_in[3];
    const float* bnm  = (const float*)d_in[4];
    const float* bnv  = (const float*)d_in[5];
    const float* dww  = (const float*)d_in[6];
    const float* dwb  = (const float*)d_in[7];
    const float* pww  = (const float*)d_in[8];
    // d_in[9] (pw_bias) unused: constant per (b,t) row -> outputs invariant.
    float* out = (float*)d_out;

    // SCH=32 (16 waves/CU) when workspace allows, else SCH=16 fallback
    const size_t part32 = (size_t)32 * BATCH * NT * HWSZ;   // floats
    const size_t need32 = (part32 + 24576 + 9216) * sizeof(float);
    const bool big = ws_size >= need32;
    const size_t partN = (big ? (size_t)32 : (size_t)16) * BATCH * NT * HWSZ;

    float* partials = (float*)d_ws;
    float* wt       = (float*)d_ws + partN;
    float* pk       = wt + 24576;

    k0_prep<<<99, 256, 0, stream>>>(pww, dww, dwb, bnw, bnb, bnm, bnv, wt, pk);
    if (big) {
        kf_fused<24><<<dim3(2, 32, BATCH), 256, 0, stream>>>(x, wt, pk, partials);
        k3_mask_gather<32><<<BATCH * NT, 256, 0, stream>>>(partials, x, pos,
                                                           bnw, bnb, bnm, bnv, out);
    } else {
        kf_fused<48><<<dim3(2, 16, BATCH), 256, 0, stream>>>(x, wt, pk, partials);
        k3_mask_gather<16><<<BATCH * NT, 256, 0, stream>>>(partials, x, pos,
                                                           bnw, bnb, bnm, bnv, out);
    }
}

// Round 13
// 83.415 us; speedup vs baseline: 3.8398x; 3.8398x over previous
//
#include <hip/hip_runtime.h>
#include <math.h>

#define DIMC 768
#define BATCH 16
#define HWSZ 1024
#define NT 32

// out layout: result [16*32*768] | p [16*32*768] | mask [16*32*1024]
#define OUT_P_OFF    393216
#define OUT_MASK_OFF 786432

typedef float v4f __attribute__((ext_vector_type(4)));

// ---------------- K0: pack params; fold 1/6 into pw weights ----------------
// pk[c][12] = { w0..w8, dwb, bn_scale, bn_shift }  (BN per tap in KF; folding
// shift into bias is WRONG at zero-padded borders -- round-9 bug)
// wt[c][t]  = pww[t][c] / 6   (hardswish divisor folded in; exact)
__global__ __launch_bounds__(256) void k0_prep(
    const float* __restrict__ pww,
    const float* __restrict__ dww, const float* __restrict__ dwb,
    const float* __restrict__ bnw, const float* __restrict__ bnb,
    const float* __restrict__ bnm, const float* __restrict__ bnv,
    float* __restrict__ wt, float* __restrict__ pk)
{
    int i = blockIdx.x * 256 + threadIdx.x;
    if (i < 24576) wt[i] = pww[(i & 31) * DIMC + (i >> 5)] * (1.0f / 6.0f);
    int c = i - 24576;
    if (c >= 0 && c < DIMC) {
        float* o = pk + c * 12;
#pragma unroll
        for (int j = 0; j < 9; ++j) o[j] = dww[c * 9 + j];
        o[9] = dwb[c];
        float scale = bnw[c] * rsqrtf(bnv[c] + 1e-5f);
        o[10] = scale;
        o[11] = bnb[c] - bnm[c] * scale;
    }
}

// ---------------- KF: fused BN + dw3x3 + hardswish + pointwise -------------
// NO LDS. Lane owns a 1x2 output strip; 3x4 window = 9 global loads.
// BN per tap: tap = fmaf(x, scale, shift) * mask (mask=0 -> f-space zero pad).
// Depth-3 register prefetch. Occupancy from the GRID (1024 blocks = 4/CU =
// 4 waves/SIMD); NO min-waves launch_bounds — round 12 proved forcing it
// spills the accumulators to scratch (VGPR 120->64, FETCH 26->408 MB).

#define DECL_SET(S) float S##l0, S##r0, S##l1, S##r1, S##l2, S##r2; \
                    float2 S##m0, S##m1, S##m2;

#define XLOAD(S, xc) { \
    S##l0 = (xc)[oL0]; S##m0 = *(const float2*)((xc) + oM0); S##r0 = (xc)[oR0]; \
    S##l1 = (xc)[oL1]; S##m1 = *(const float2*)((xc) + oM1); S##r1 = (xc)[oR1]; \
    S##l2 = (xc)[oL2]; S##m2 = *(const float2*)((xc) + oM2); S##r2 = (xc)[oR2]; }

#define STEP(k, S, ISSUE) { \
    const float* pr = pkb + (k) * 12; \
    v4f P0 = *(const v4f*)pr; \
    v4f P1 = *(const v4f*)(pr + 4); \
    v4f P2 = *(const v4f*)(pr + 8);      /* {w8, dwb, scale, shift} */ \
    const float sc_ = P2.z, sh_ = P2.w; \
    float a0  = fmaf(S##l0,   sc_, sh_) * mL0; \
    float b0x = fmaf(S##m0.x, sc_, sh_) * mM0; \
    float b0y = fmaf(S##m0.y, sc_, sh_) * mM0; \
    float c0  = fmaf(S##r0,   sc_, sh_) * mR0; \
    float a1  = fmaf(S##l1,   sc_, sh_) * mL1; \
    float b1x = fmaf(S##m1.x, sc_, sh_) * mM1; \
    float b1y = fmaf(S##m1.y, sc_, sh_) * mM1; \
    float c1  = fmaf(S##r1,   sc_, sh_) * mR1; \
    float a2  = fmaf(S##l2,   sc_, sh_) * mL2; \
    float b2x = fmaf(S##m2.x, sc_, sh_) * mM2; \
    float b2y = fmaf(S##m2.y, sc_, sh_) * mM2; \
    float c2  = fmaf(S##r2,   sc_, sh_) * mR2; \
    if (ISSUE) { XLOAD(S, xcur); xcur += HWSZ; } \
    float s0 = P2.y, s1 = P2.y; \
    s0 = fmaf(P0.x, a0,  s0); s1 = fmaf(P0.x, b0x, s1); \
    s0 = fmaf(P0.y, b0x, s0); s1 = fmaf(P0.y, b0y, s1); \
    s0 = fmaf(P0.z, b0y, s0); s1 = fmaf(P0.z, c0,  s1); \
    s0 = fmaf(P0.w, a1,  s0); s1 = fmaf(P0.w, b1x, s1); \
    s0 = fmaf(P1.x, b1x, s0); s1 = fmaf(P1.x, b1y, s1); \
    s0 = fmaf(P1.y, b1y, s0); s1 = fmaf(P1.y, c1,  s1); \
    s0 = fmaf(P1.z, a2,  s0); s1 = fmaf(P1.z, b2x, s1); \
    s0 = fmaf(P1.w, b2x, s0); s1 = fmaf(P1.w, b2y, s1); \
    s0 = fmaf(P2.x, b2y, s0); s1 = fmaf(P2.x, c2,  s1); \
    float h0 = s0 * fminf(fmaxf(s0 + 3.0f, 0.0f), 6.0f); \
    float h1 = s1 * fminf(fmaxf(s1 + 3.0f, 0.0f), 6.0f); \
    v4f hv0 = {h0, h0, h0, h0}, hv1 = {h1, h1, h1, h1}; \
    const v4f* wr = (const v4f*)(wtb + (k) * NT); \
    A0 = __builtin_elementwise_fma(hv0, wr[0], A0); B0 = __builtin_elementwise_fma(hv1, wr[0], B0); \
    A1 = __builtin_elementwise_fma(hv0, wr[1], A1); B1 = __builtin_elementwise_fma(hv1, wr[1], B1); \
    A2 = __builtin_elementwise_fma(hv0, wr[2], A2); B2 = __builtin_elementwise_fma(hv1, wr[2], B2); \
    A3 = __builtin_elementwise_fma(hv0, wr[3], A3); B3 = __builtin_elementwise_fma(hv1, wr[3], B3); \
    A4 = __builtin_elementwise_fma(hv0, wr[4], A4); B4 = __builtin_elementwise_fma(hv1, wr[4], B4); \
    A5 = __builtin_elementwise_fma(hv0, wr[5], A5); B5 = __builtin_elementwise_fma(hv1, wr[5], B5); \
    A6 = __builtin_elementwise_fma(hv0, wr[6], A6); B6 = __builtin_elementwise_fma(hv1, wr[6], B6); \
    A7 = __builtin_elementwise_fma(hv0, wr[7], A7); B7 = __builtin_elementwise_fma(hv1, wr[7], B7); }

#define ST4(G) { \
    float2 v; \
    v.x = A##G.x; v.y = B##G.x; *(float2*)(po + ((4*G+0) << 10)) = v; \
    v.x = A##G.y; v.y = B##G.y; *(float2*)(po + ((4*G+1) << 10)) = v; \
    v.x = A##G.z; v.y = B##G.z; *(float2*)(po + ((4*G+2) << 10)) = v; \
    v.x = A##G.w; v.y = B##G.w; *(float2*)(po + ((4*G+3) << 10)) = v; }

template<int CHPB>
__global__ __launch_bounds__(256) void kf_fused(
    const float* __restrict__ x,
    const float* __restrict__ wt, const float* __restrict__ pk,
    float* __restrict__ partials)
{
    const int b    = blockIdx.z;
    const int scc  = blockIdx.y;
    const int cb0  = scc * CHPB;
    const int tid  = threadIdx.x;
    const int wv   = tid >> 6;
    const int lane = tid & 63;
    const int rl   = lane >> 4;               // 0..3
    const int cp   = lane & 15;
    const int col0 = cp * 2;
    const int gr0  = blockIdx.x * 16 + wv * 4 + rl;   // output row 0..31

    // window geometry: rows gr0-1..gr0+1, cols col0-1..col0+2
    // clamped offsets (always-safe loads) + 0/1 mask floats (f-space zero pad)
    int gr, grc; float rv;
    gr = gr0 - 1; grc = gr < 0 ? 0 : (gr > 31 ? 31 : gr);
    rv = (gr >= 0 && gr < 32) ? 1.0f : 0.0f;
    const int   oM0 = grc * 32 + col0;
    const int   oL0 = grc * 32 + (cp ? col0 - 1 : 0);
    const int   oR0 = grc * 32 + (cp < 15 ? col0 + 2 : 31);
    const float mM0 = rv, mL0 = cp ? rv : 0.0f, mR0 = (cp < 15) ? rv : 0.0f;
    gr = gr0;
    const int   oM1 = gr * 32 + col0;
    const int   oL1 = gr * 32 + (cp ? col0 - 1 : 0);
    const int   oR1 = gr * 32 + (cp < 15 ? col0 + 2 : 31);
    const float mM1 = 1.0f, mL1 = cp ? 1.0f : 0.0f, mR1 = (cp < 15) ? 1.0f : 0.0f;
    gr = gr0 + 1; grc = gr > 31 ? 31 : gr;
    rv = (gr < 32) ? 1.0f : 0.0f;
    const int   oM2 = grc * 32 + col0;
    const int   oL2 = grc * 32 + (cp ? col0 - 1 : 0);
    const int   oR2 = grc * 32 + (cp < 15 ? col0 + 2 : 31);
    const float mM2 = rv, mL2 = cp ? rv : 0.0f, mR2 = (cp < 15) ? rv : 0.0f;

    const float* xb  = x  + (size_t)(b * DIMC + cb0) * HWSZ;
    const float* pkb = pk + (size_t)cb0 * 12;
    const float* wtb = wt + (size_t)cb0 * NT;

    DECL_SET(SA) DECL_SET(SB) DECL_SET(SC)

    // prologue: prefetch channels 0..2 (depth 3)
    const float* xcur = xb;
    XLOAD(SA, xcur); xcur += HWSZ;
    XLOAD(SB, xcur); xcur += HWSZ;
    XLOAD(SC, xcur); xcur += HWSZ;

    v4f A0 = {0,0,0,0}, A1 = {0,0,0,0}, A2 = {0,0,0,0}, A3 = {0,0,0,0};
    v4f A4 = {0,0,0,0}, A5 = {0,0,0,0}, A6 = {0,0,0,0}, A7 = {0,0,0,0};
    v4f B0 = {0,0,0,0}, B1 = {0,0,0,0}, B2 = {0,0,0,0}, B3 = {0,0,0,0};
    v4f B4 = {0,0,0,0}, B5 = {0,0,0,0}, B6 = {0,0,0,0}, B7 = {0,0,0,0};

    for (int k = 0; k < CHPB - 3; k += 3) {
        STEP(k + 0, SA, 1)
        STEP(k + 1, SB, 1)
        STEP(k + 2, SC, 1)
    }
    STEP(CHPB - 3, SA, 0)
    STEP(CHPB - 2, SB, 0)
    STEP(CHPB - 1, SC, 0)

    // epilogue: token t gets float2 {pos, pos+1}
    const int pos = gr0 * 32 + col0;
    float* po = partials + ((size_t)(scc * BATCH + b) * NT) * HWSZ + pos;
    ST4(0) ST4(1) ST4(2) ST4(3) ST4(4) ST4(5) ST4(6) ST4(7)
}

// ---------------- K3: sum partials -> argmax mask -> gather-sum ------------
template<int SCHT>
__global__ __launch_bounds__(256) void k3_mask_gather(
    const float* __restrict__ partials,
    const float* __restrict__ x, const float* __restrict__ posin,
    const float* __restrict__ bnw, const float* __restrict__ bnb,
    const float* __restrict__ bnm, const float* __restrict__ bnv,
    float* __restrict__ out)
{
    int bt = blockIdx.x;           // b*32 + t
    int b  = bt >> 5;
    int t  = bt & 31;
    int tid = threadIdx.x;

    const float4* pp4 = (const float4*)(partials + ((size_t)(b * NT) + t) * HWSZ) + tid;
    float4 acc = make_float4(0.f, 0.f, 0.f, 0.f);
#pragma unroll
    for (int s = 0; s < SCHT; ++s) {
        float4 u = pp4[(size_t)s * (BATCH * NT * HWSZ / 4)];
        acc.x += u.x; acc.y += u.y; acc.z += u.z; acc.w += u.w;
    }

    float m = fmaxf(fmaxf(acc.x, acc.y), fmaxf(acc.z, acc.w));
#pragma unroll
    for (int off = 32; off; off >>= 1)
        m = fmaxf(m, __shfl_xor(m, off));
    __shared__ float wm[4];
    if ((tid & 63) == 0) wm[tid >> 6] = m;
    __syncthreads();
    m = fmaxf(fmaxf(wm[0], wm[1]), fmaxf(wm[2], wm[3]));

    __shared__ int nmatch;
    __shared__ int matchpos[16];
    if (tid == 0) nmatch = 0;
    __syncthreads();

    float* maskp = out + OUT_MASK_OFF + (size_t)bt * HWSZ;
    float4 mask4;
    const float* av = &acc.x;
    float* mv = &mask4.x;
#pragma unroll
    for (int j = 0; j < 4; ++j) {
        int hit = (av[j] == m);
        mv[j] = hit ? 1.0f : 0.0f;
        if (hit) {
            int k = atomicAdd(&nmatch, 1);
            if (k < 16) matchpos[k] = 4 * tid + j;
        }
    }
    ((float4*)maskp)[tid] = mask4;
    __syncthreads();
    int nm = nmatch < 16 ? nmatch : 16;

    const float* xb = x + (size_t)b * DIMC * HWSZ;
    const float* pb = posin + (size_t)b * DIMC * HWSZ;
    for (int c = tid; c < DIMC; c += 256) {
        float scale = bnw[c] * rsqrtf(bnv[c] + 1e-5f);
        float shift = bnb[c] - bnm[c] * scale;
        float rf = 0.0f, rp = 0.0f;
        for (int k = 0; k < nm; ++k) {
            int pos = matchpos[k];
            rf += xb[(size_t)c * HWSZ + pos] * scale + shift;
            rp += pb[(size_t)c * HWSZ + pos];
        }
        out[(size_t)bt * DIMC + c] = rf;
        out[OUT_P_OFF + (size_t)bt * DIMC + c] = rp;
    }
}

extern "C" void kernel_launch(void* const* d_in, const int* in_sizes, int n_in,
                              void* d_out, int out_size, void* d_ws, size_t ws_size,
                              hipStream_t stream)
{
    const float* x    = (const float*)d_in[0];
    const float* pos  = (const float*)d_in[1];
    const float* bnw  = (const float*)d_in[2];
    const float* bnb  = (const float*)d_in[3];
    const float* bnm  = (const float*)d_in[4];
    const float* bnv  = (const float*)d_in[5];
    const float* dww  = (const float*)d_in[6];
    const float* dwb  = (const float*)d_in[7];
    const float* pww  = (const float*)d_in[8];
    // d_in[9] (pw_bias) unused: constant per (b,t) row -> outputs invariant.
    float* out = (float*)d_out;

    // SCH=32 (4 blocks/CU) when workspace allows, else SCH=16 fallback
    const size_t part32 = (size_t)32 * BATCH * NT * HWSZ;   // floats
    const size_t need32 = (part32 + 24576 + 9216) * sizeof(float);
    const bool big = ws_size >= need32;
    const size_t partN = (big ? (size_t)32 : (size_t)16) * BATCH * NT * HWSZ;

    float* partials = (float*)d_ws;
    float* wt       = (float*)d_ws + partN;
    float* pk       = wt + 24576;

    k0_prep<<<99, 256, 0, stream>>>(pww, dww, dwb, bnw, bnb, bnm, bnv, wt, pk);
    if (big) {
        kf_fused<24><<<dim3(2, 32, BATCH), 256, 0, stream>>>(x, wt, pk, partials);
        k3_mask_gather<32><<<BATCH * NT, 256, 0, stream>>>(partials, x, pos,
                                                           bnw, bnb, bnm, bnv, out);
    } else {
        kf_fused<48><<<dim3(2, 16, BATCH), 256, 0, stream>>>(x, wt, pk, partials);
        k3_mask_gather<16><<<BATCH * NT, 256, 0, stream>>>(partials, x, pos,
                                                           bnw, bnb, bnm, bnv, out);
    }
}

// Round 14
// 65.240 us; speedup vs baseline: 4.9096x; 1.2786x over previous
//
#include <hip/hip_runtime.h>
#include <math.h>

#define DIMC 768
#define BATCH 16
#define HWSZ 1024
#define NT 32

// out layout: result [16*32*768] | p [16*32*768] | mask [16*32*1024]
#define OUT_P_OFF    393216
#define OUT_MASK_OFF 786432

typedef float v4f __attribute__((ext_vector_type(4)));

// ---------------- K0: transpose pww -> wt[c][t]; pack per-channel params ---
// pk[c][12] = { dw[0..8], dw_bias, bn_scale, bn_shift } (48B rows, 16B-aligned)
__global__ __launch_bounds__(256) void k0_prep(
    const float* __restrict__ pww,
    const float* __restrict__ dww, const float* __restrict__ dwb,
    const float* __restrict__ bnw, const float* __restrict__ bnb,
    const float* __restrict__ bnm, const float* __restrict__ bnv,
    float* __restrict__ wt, float* __restrict__ pk)
{
    int i = blockIdx.x * 256 + threadIdx.x;
    if (i < 24576) wt[i] = pww[(i & 31) * DIMC + (i >> 5)];
    int c = i - 24576;
    if (c >= 0 && c < DIMC) {
        float* o = pk + c * 12;
#pragma unroll
        for (int j = 0; j < 9; ++j) o[j] = dww[c * 9 + j];
        o[9] = dwb[c];
        float scale = bnw[c] * rsqrtf(bnv[c] + 1e-5f);
        o[10] = scale;
        o[11] = bnb[c] - bnm[c] * scale;
    }
}

// ---------------- KF: fused BN + dw3x3 + hardswish + pointwise partials ----
// round-7 structure verbatim (measured 40 us): 256 thr, one position/lane,
// one channel per barrier-iter, LDS double-buffer, depth-3 register prefetch.
template<int CHPB>
__global__ __launch_bounds__(256) void kf_fused(
    const float* __restrict__ x,
    const float* __restrict__ wt, const float* __restrict__ pk,
    float* __restrict__ partials)
{
    const int b   = blockIdx.z;
    const int scc = blockIdx.y;
    const int cb0 = scc * CHPB;
    const int r0  = blockIdx.x * 8;           // first output row
    const int tid = threadIdx.x;
    const int rl  = tid >> 5;
    const int col = tid & 31;

    __shared__ float st[2][340];              // zero-padded 10x34 halo tiles
    for (int i = tid; i < 680; i += 256) ((float*)st)[i] = 0.0f;

    // staging geometry: slots tid and tid+256 over [10][34]
    const int i1  = tid + 256;
    const int sr0 = tid / 34, sc0 = tid - sr0 * 34;
    const int sr1 = i1 / 34,  sc1 = i1 - sr1 * 34;
    const int rr0 = r0 - 1 + sr0, cl0 = sc0 - 1;
    const int rr1 = r0 - 1 + sr1, cl1 = sc1 - 1;
    const bool va = rr0 >= 0 && rr0 < 32 && cl0 >= 0 && cl0 < 32;
    const bool vb = (i1 < 340) && rr1 >= 0 && rr1 < 32 && cl1 >= 0 && cl1 < 32;
    const int  oa = rr0 * 32 + cl0, ob = rr1 * 32 + cl1;

    const float* xb  = x  + (size_t)(b * DIMC + cb0) * HWSZ;
    const float* pkb = pk + (size_t)cb0 * 12;
    const float* wtb = wt + (size_t)cb0 * NT;

    // prologue: stage ch0 to LDS; issue ch1, ch2 into registers
    {
        float sc = pkb[10], sh = pkb[11];
        if (va) st[0][tid] = fmaf(xb[oa], sc, sh);
        if (vb) st[0][i1]  = fmaf(xb[ob], sc, sh);
    }
    float g1a = 0.f, g1b = 0.f, g2a = 0.f, g2b = 0.f;
    if (va) g1a = xb[(size_t)1 * HWSZ + oa];
    if (vb) g1b = xb[(size_t)1 * HWSZ + ob];
    if (va) g2a = xb[(size_t)2 * HWSZ + oa];
    if (vb) g2b = xb[(size_t)2 * HWSZ + ob];
    __syncthreads();

    v4f A0 = {0,0,0,0}, A1 = {0,0,0,0}, A2 = {0,0,0,0}, A3 = {0,0,0,0};
    v4f A4 = {0,0,0,0}, A5 = {0,0,0,0}, A6 = {0,0,0,0}, A7 = {0,0,0,0};
    const int base = rl * 34 + col;

    for (int k = 0; k < CHPB; ++k) {
        const float* S = &st[k & 1][base];

        // issue loads for channel k+3 (consumed 2 barriers later)
        float g3a = 0.f, g3b = 0.f;
        if (k + 3 < CHPB) {
            if (va) g3a = xb[(size_t)(k + 3) * HWSZ + oa];
            if (vb) g3b = xb[(size_t)(k + 3) * HWSZ + ob];
        }

        // depthwise 3x3 + hardswish (params via uniform s_load)
        const float* pr = pkb + k * 12;
        v4f P0 = *(const v4f*)(pr + 0);
        v4f P1 = *(const v4f*)(pr + 4);
        v4f P2 = *(const v4f*)(pr + 8);       // {w8, dwb, scale, shift}
        float r = P2.y;
        r = fmaf(P0.x, S[ 0], r);
        r = fmaf(P0.y, S[ 1], r);
        r = fmaf(P0.z, S[ 2], r);
        r = fmaf(P0.w, S[34], r);
        r = fmaf(P1.x, S[35], r);
        r = fmaf(P1.y, S[36], r);
        r = fmaf(P1.z, S[68], r);
        r = fmaf(P1.w, S[69], r);
        r = fmaf(P2.x, S[70], r);
        float clp = fminf(fmaxf(r + 3.0f, 0.0f), 6.0f);
        float hs  = r * clp * (1.0f / 6.0f);

        // pointwise: 32 token FMAs (weights uniform)
        const float* wr = wtb + k * NT;
        v4f hv = {hs, hs, hs, hs};
        A0 = __builtin_elementwise_fma(hv, *(const v4f*)(wr +  0), A0);
        A1 = __builtin_elementwise_fma(hv, *(const v4f*)(wr +  4), A1);
        A2 = __builtin_elementwise_fma(hv, *(const v4f*)(wr +  8), A2);
        A3 = __builtin_elementwise_fma(hv, *(const v4f*)(wr + 12), A3);
        A4 = __builtin_elementwise_fma(hv, *(const v4f*)(wr + 16), A4);
        A5 = __builtin_elementwise_fma(hv, *(const v4f*)(wr + 20), A5);
        A6 = __builtin_elementwise_fma(hv, *(const v4f*)(wr + 24), A6);
        A7 = __builtin_elementwise_fma(hv, *(const v4f*)(wr + 28), A7);

        // late BN + LDS write of channel k+1 (loaded 2 iters ago)
        if (k + 1 < CHPB) {
            float sc = pkb[(k + 1) * 12 + 10], sh = pkb[(k + 1) * 12 + 11];
            float* Sn = &st[(k & 1) ^ 1][0];
            if (va) Sn[tid] = fmaf(g1a, sc, sh);
            if (vb) Sn[i1]  = fmaf(g1b, sc, sh);
        }
        g1a = g2a; g1b = g2b; g2a = g3a; g2b = g3b;
        __syncthreads();
    }

    float* po = partials + ((size_t)(scc * BATCH + b) * NT) * HWSZ
              + blockIdx.x * 256 + tid;
    po[ 0 << 10] = A0.x; po[ 1 << 10] = A0.y; po[ 2 << 10] = A0.z; po[ 3 << 10] = A0.w;
    po[ 4 << 10] = A1.x; po[ 5 << 10] = A1.y; po[ 6 << 10] = A1.z; po[ 7 << 10] = A1.w;
    po[ 8 << 10] = A2.x; po[ 9 << 10] = A2.y; po[10 << 10] = A2.z; po[11 << 10] = A2.w;
    po[12 << 10] = A3.x; po[13 << 10] = A3.y; po[14 << 10] = A3.z; po[15 << 10] = A3.w;
    po[16 << 10] = A4.x; po[17 << 10] = A4.y; po[18 << 10] = A4.z; po[19 << 10] = A4.w;
    po[20 << 10] = A5.x; po[21 << 10] = A5.y; po[22 << 10] = A5.z; po[23 << 10] = A5.w;
    po[24 << 10] = A6.x; po[25 << 10] = A6.y; po[26 << 10] = A6.z; po[27 << 10] = A6.w;
    po[28 << 10] = A7.x; po[29 << 10] = A7.y; po[30 << 10] = A7.z; po[31 << 10] = A7.w;
}

// ---------------- K3a: sum partials -> argmax -> mask + match list ---------
// match[bt*20] = nm; match[bt*20 + 1 + k] = k-th tied position
template<int SCHT>
__global__ __launch_bounds__(256) void k3a_mask(
    const float* __restrict__ partials,
    float* __restrict__ out, int* __restrict__ match)
{
    int bt = blockIdx.x;           // b*32 + t
    int b  = bt >> 5;
    int t  = bt & 31;
    int tid = threadIdx.x;

    const float4* pp4 = (const float4*)(partials + ((size_t)(b * NT) + t) * HWSZ) + tid;
    float4 acc = make_float4(0.f, 0.f, 0.f, 0.f);
#pragma unroll
    for (int s = 0; s < SCHT; ++s) {
        float4 u = pp4[(size_t)s * (BATCH * NT * HWSZ / 4)];
        acc.x += u.x; acc.y += u.y; acc.z += u.z; acc.w += u.w;
    }

    float m = fmaxf(fmaxf(acc.x, acc.y), fmaxf(acc.z, acc.w));
#pragma unroll
    for (int off = 32; off; off >>= 1)
        m = fmaxf(m, __shfl_xor(m, off));
    __shared__ float wm[4];
    if ((tid & 63) == 0) wm[tid >> 6] = m;
    __syncthreads();
    m = fmaxf(fmaxf(wm[0], wm[1]), fmaxf(wm[2], wm[3]));

    __shared__ int nmatch;
    __shared__ int matchpos[16];
    if (tid == 0) nmatch = 0;
    __syncthreads();

    float* maskp = out + OUT_MASK_OFF + (size_t)bt * HWSZ;
    float4 mask4;
    const float* av = &acc.x;
    float* mv = &mask4.x;
#pragma unroll
    for (int j = 0; j < 4; ++j) {
        int hit = (av[j] == m);
        mv[j] = hit ? 1.0f : 0.0f;
        if (hit) {
            int k = atomicAdd(&nmatch, 1);
            if (k < 16) matchpos[k] = 4 * tid + j;
        }
    }
    ((float4*)maskp)[tid] = mask4;
    __syncthreads();

    int nm = nmatch < 16 ? nmatch : 16;
    if (tid == 0) match[bt * 20] = nm;
    if (tid < nm) match[bt * 20 + 1 + tid] = matchpos[tid];
}

// ---------------- K3b: gather-sum (one channel per lane, max MLP) ----------
// grid (cchunk=3, bt=512), 256 thr; nm/matchpos uniform -> s_load broadcast.
__global__ __launch_bounds__(256) void k3b_gather(
    const int* __restrict__ match,
    const float* __restrict__ x, const float* __restrict__ posin,
    const float* __restrict__ bnw, const float* __restrict__ bnb,
    const float* __restrict__ bnm, const float* __restrict__ bnv,
    float* __restrict__ out)
{
    const int bt = blockIdx.y;
    const int b  = bt >> 5;
    const int c  = blockIdx.x * 256 + threadIdx.x;   // < 768

    int nm = match[bt * 20];
    nm = nm < 16 ? nm : 16;

    float scale = bnw[c] * rsqrtf(bnv[c] + 1e-5f);
    float shift = bnb[c] - bnm[c] * scale;

    const float* xc = x     + (size_t)(b * DIMC + c) * HWSZ;
    const float* pc = posin + (size_t)(b * DIMC + c) * HWSZ;

    float rf = 0.0f, rp = 0.0f;
    for (int k = 0; k < nm; ++k) {
        int pos = match[bt * 20 + 1 + k];
        rf += fmaf(xc[pos], scale, shift);
        rp += pc[pos];
    }
    out[(size_t)bt * DIMC + c] = rf;
    out[OUT_P_OFF + (size_t)bt * DIMC + c] = rp;
}

extern "C" void kernel_launch(void* const* d_in, const int* in_sizes, int n_in,
                              void* d_out, int out_size, void* d_ws, size_t ws_size,
                              hipStream_t stream)
{
    const float* x    = (const float*)d_in[0];
    const float* pos  = (const float*)d_in[1];
    const float* bnw  = (const float*)d_in[2];
    const float* bnb  = (const float*)d_in[3];
    const float* bnm  = (const float*)d_in[4];
    const float* bnv  = (const float*)d_in[5];
    const float* dww  = (const float*)d_in[6];
    const float* dwb  = (const float*)d_in[7];
    const float* pww  = (const float*)d_in[8];
    // d_in[9] (pw_bias) unused: constant per (b,t) row -> outputs invariant.
    float* out = (float*)d_out;

    // SCH=32 (better TLP; round-7 measured best) when workspace allows
    const size_t part32 = (size_t)32 * BATCH * NT * HWSZ;   // floats
    const size_t need32 = (part32 + 24576 + 9216 + 10240) * sizeof(float);
    const bool big = ws_size >= need32;
    const size_t partN = (big ? (size_t)32 : (size_t)16) * BATCH * NT * HWSZ;

    float* partials = (float*)d_ws;
    float* wt       = (float*)d_ws + partN;
    float* pk       = wt + 24576;
    int*   match    = (int*)(pk + 9216);

    k0_prep<<<99, 256, 0, stream>>>(pww, dww, dwb, bnw, bnb, bnm, bnv, wt, pk);
    if (big) {
        kf_fused<24><<<dim3(4, 32, BATCH), 256, 0, stream>>>(x, wt, pk, partials);
        k3a_mask<32><<<BATCH * NT, 256, 0, stream>>>(partials, out, match);
    } else {
        kf_fused<48><<<dim3(4, 16, BATCH), 256, 0, stream>>>(x, wt, pk, partials);
        k3a_mask<16><<<BATCH * NT, 256, 0, stream>>>(partials, out, match);
    }
    k3b_gather<<<dim3(3, BATCH * NT), 256, 0, stream>>>(match, x, pos,
                                                        bnw, bnb, bnm, bnv, out);
}